// Round 6
// baseline (639.232 us; speedup 1.0000x reference)
//
#include <hip/hip_runtime.h>
#include <stdint.h>

#define TSTEPS 1000
#define NB 256
#define NF 64
#define NH 256   // H1 == H2 == 256
#define CHUNK 8
#define NCH 125  // 125 * 8 == 1000, no tail

// Prep: transpose W2 (H2,H1) -> W2T[h1][h2] in d_ws for coalesced gathers,
// and zero the two global spike counters.
__global__ void snn_prep(const float* __restrict__ W2, float* __restrict__ W2T,
                         unsigned int* __restrict__ counts) {
    int idx = blockIdx.x * 256 + threadIdx.x;     // idx = h1*256 + h2
    W2T[idx] = W2[(idx & 255) * 256 + (idx >> 8)];
    if (idx < 2) counts[idx] = 0u;
}

// One FMA quad: acc += x.{xyzw} * w.{xyzw}, ascending feature order.
// fma(1,w,a)=round(a+w) and fma(0,w,a)=a exactly, so this is bit-identical
// to the original masked-add form for x in {0,1}.
#define FMAQ(acc, xv, wv) \
    acc += xv.x * wv.x; acc += xv.y * wv.y; acc += xv.z * wv.z; acc += xv.w * wv.w;

// Producer step: uniform x row (scalar loads), 4 chains of 16 features
// (same grouping as all previous passing rounds), mem1 update, spk1 publish.
// NO arrays anywhere -> mem2reg promotes everything to registers (round-5
// lesson: VGPR=88 proved w1[64]/xv[16] arrays were scratch-backed; the
// per-use re-loads were the dominant stall).
#define PSTEP(pb, tt) do {                                                    \
    const float4* xr4 =                                                       \
        (const float4*)(xrow_base + (size_t)(tb + (tt)) * xstride);           \
    float4 x0 = xr4[0],  x1 = xr4[1],  x2 = xr4[2],  x3 = xr4[3];             \
    float4 x4 = xr4[4],  x5 = xr4[5],  x6 = xr4[6],  x7 = xr4[7];             \
    float4 x8 = xr4[8],  x9 = xr4[9],  x10 = xr4[10], x11 = xr4[11];          \
    float4 x12 = xr4[12], x13 = xr4[13], x14 = xr4[14], x15 = xr4[15];        \
    float a0 = 0.f, a1 = 0.f, a2 = 0.f, a3 = 0.f;                             \
    FMAQ(a0, x0,  wq0)  FMAQ(a0, x1,  wq1)  FMAQ(a0, x2,  wq2)  FMAQ(a0, x3,  wq3)  \
    FMAQ(a1, x4,  wq4)  FMAQ(a1, x5,  wq5)  FMAQ(a1, x6,  wq6)  FMAQ(a1, x7,  wq7)  \
    FMAQ(a2, x8,  wq8)  FMAQ(a2, x9,  wq9)  FMAQ(a2, x10, wq10) FMAQ(a2, x11, wq11) \
    FMAQ(a3, x12, wq12) FMAQ(a3, x13, wq13) FMAQ(a3, x14, wq14) FMAQ(a3, x15, wq15) \
    float cur1 = b1h + ((a0 + a1) + (a2 + a3));                               \
    float reset1 = (mem1 > 1.f) ? 1.f : 0.f;                                  \
    mem1 = 0.8187307530779818f * mem1 + cur1 - reset1; /* beta1=exp(-1/5) */  \
    bool s1 = (mem1 - 1.f) > 0.f;                                             \
    cnt1 += (int)s1;                                                          \
    unsigned long long sm = __ballot(s1);                                     \
    if (lane == 0) scnt8[pb][(tt) * 4 + wv] = (unsigned char)__popcll(sm);    \
    if (s1) {                                                                 \
        int rank = __popcll(sm & ((1ull << lane) - 1ull));                    \
        slist[pb][tt][(wv << 6) + rank] = (unsigned char)h;                   \
    }                                                                         \
} while (0)

// Consumer step: read the 5 metadata words (named locals, no hoist arrays),
// branch-free first-4 gather with value masking (order matches the guarded
// loop exactly), rare overflow path, mem2 update.
#define CSTEP(cb, tt) do {                                                    \
    unsigned int cwv = *(const unsigned int*)&scnt8[cb][(tt) * 4];            \
    unsigned int u0 = *(const unsigned int*)&slist[cb][tt][0];                \
    unsigned int u1 = *(const unsigned int*)&slist[cb][tt][64];               \
    unsigned int u2 = *(const unsigned int*)&slist[cb][tt][128];              \
    unsigned int u3 = *(const unsigned int*)&slist[cb][tt][192];              \
    int c0 = (int)(cwv & 255u),        c1 = (int)((cwv >> 8) & 255u);         \
    int c2 = (int)((cwv >> 16) & 255u), c3 = (int)((cwv >> 24) & 255u);       \
    float q0 = 0.f, q1 = 0.f, q2 = 0.f, q3 = 0.f;                             \
    _Pragma("unroll")                                                         \
    for (int i = 0; i < 4; ++i) {                                             \
        float v0 = W2Th[(int)((u0 >> (8 * i)) & 255u) << 8];                  \
        float v1 = W2Th[(int)((u1 >> (8 * i)) & 255u) << 8];                  \
        float v2 = W2Th[(int)((u2 >> (8 * i)) & 255u) << 8];                  \
        float v3 = W2Th[(int)((u3 >> (8 * i)) & 255u) << 8];                  \
        q0 += (i < c0) ? v0 : 0.f;                                            \
        q1 += (i < c1) ? v1 : 0.f;                                            \
        q2 += (i < c2) ? v2 : 0.f;                                            \
        q3 += (i < c3) ? v3 : 0.f;                                            \
    }                                                                         \
    int nmax = max(max(c0, c1), max(c2, c3));                                 \
    if (nmax > 4) {   /* rare overflow path (per-wave spike count > 4) */     \
        const unsigned char* sl = &slist[cb][tt][0];                          \
        for (int i = 4; i < nmax; ++i) {                                      \
            if (i < c0) q0 += W2Th[(int)sl[i] << 8];                          \
            if (i < c1) q1 += W2Th[(int)sl[64 + i] << 8];                     \
            if (i < c2) q2 += W2Th[(int)sl[128 + i] << 8];                    \
            if (i < c3) q3 += W2Th[(int)sl[192 + i] << 8];                    \
        }                                                                     \
    }                                                                         \
    float cur2 = b2h + ((q0 + q1) + (q2 + q3));                               \
    float reset2 = (mem2 > 1.f) ? 1.f : 0.f;                                  \
    mem2 = 0.9048374180359595f * mem2 + cur2 - reset2; /* beta2=exp(-1/10) */ \
    bool s2 = (mem2 - 1.f) > 0.f;                                             \
    cnt2 += (int)s2;                                                          \
    mem2s += mem2;                                                            \
} while (0)

// Main: one 512-thread workgroup per batch, wave-specialized pipeline.
//   waves 0-3 (producer): own mem1[h], run layer 1 for chunk c, publish
//                         spk1 lists to slist[c&1].
//   waves 4-7 (consumer): own mem2[h], run layer 2 for chunk c-1.
__launch_bounds__(512, 2)
__global__ void snn_main(const float* __restrict__ spikes,
                         const float* __restrict__ W1,
                         const float* __restrict__ b1,
                         const float* __restrict__ W2T,
                         const float* __restrict__ b2,
                         const float* __restrict__ Wr,
                         const float* __restrict__ br,
                         float* __restrict__ out,
                         unsigned int* __restrict__ counts) {
    const int b = blockIdx.x;
    const int tid = threadIdx.x;
    const int lane = tid & 63;
    const int wv = tid >> 6;          // 0..7
    const bool producer = (wv < 4);
    const int h = tid & 255;          // hidden index within the role group

    __shared__ unsigned char slist[2][CHUNK][256]; // per-chunk-buf spk1 lists
    __shared__ unsigned char scnt8[2][CHUNK * 4];  // per-step per-wave counts
    __shared__ float rp0[4], rp1[4];
    __shared__ int rc1[4], rc2[4];

    const size_t xstride = (size_t)NB * NF;
    const float* xrow_base = spikes + (size_t)b * NF;   // uniform row base
    const float* xbase = xrow_base + lane;              // per-lane warm ptr
    const float* W2Th = W2T + h;

    // W1 row h as 16 NAMED float4 registers (no array -> mem2reg promotes;
    // ~160 live VGPRs fits the 256-VGPR budget of launch_bounds(512,2)).
    float4 wq0 = {0,0,0,0}, wq1 = {0,0,0,0}, wq2 = {0,0,0,0}, wq3 = {0,0,0,0};
    float4 wq4 = {0,0,0,0}, wq5 = {0,0,0,0}, wq6 = {0,0,0,0}, wq7 = {0,0,0,0};
    float4 wq8 = {0,0,0,0}, wq9 = {0,0,0,0}, wq10 = {0,0,0,0}, wq11 = {0,0,0,0};
    float4 wq12 = {0,0,0,0}, wq13 = {0,0,0,0}, wq14 = {0,0,0,0}, wq15 = {0,0,0,0};

    float mem1 = 0.f, mem2 = 0.f, mem2s = 0.f;
    int cnt1 = 0, cnt2 = 0;
    float b1h = 0.f, b2h = 0.f;

    if (producer) {
        const float4* W1v = (const float4*)(W1 + h * NF);
        wq0 = W1v[0];  wq1 = W1v[1];  wq2 = W1v[2];  wq3 = W1v[3];
        wq4 = W1v[4];  wq5 = W1v[5];  wq6 = W1v[6];  wq7 = W1v[7];
        wq8 = W1v[8];  wq9 = W1v[9];  wq10 = W1v[10]; wq11 = W1v[11];
        wq12 = W1v[12]; wq13 = W1v[13]; wq14 = W1v[14]; wq15 = W1v[15];
        b1h = b1[h];
    } else {
        b2h = b2[h];
    }

    for (int c = 0; c < NCH; ++c) {
        if (producer) {
            const int pb = c & 1;
            const int tb = c * CHUNK;
            // Issue next-chunk L2-warm loads FIRST (vector path shares TCC
            // with the scalar x loads); anchored at the end of this block,
            // ~2k cycles later -> no exposed latency (round-5's placement
            // stalled vmcnt(0) at chunk start instead).
            int cn = (c + 1 < NCH) ? c + 1 : 0;  // clamped dummy on last
            const float* xb = xbase + (size_t)cn * CHUNK * xstride;
            float wm0 = xb[0],           wm1 = xb[xstride];
            float wm2 = xb[2 * xstride], wm3 = xb[3 * xstride];
            float wm4 = xb[4 * xstride], wm5 = xb[5 * xstride];
            float wm6 = xb[6 * xstride], wm7 = xb[7 * xstride];
            // ---- layer 1: CHUNK steps ----
            PSTEP(pb, 0); PSTEP(pb, 1); PSTEP(pb, 2); PSTEP(pb, 3);
            PSTEP(pb, 4); PSTEP(pb, 5); PSTEP(pb, 6); PSTEP(pb, 7);
            // keep the warm loads alive (prevent DCE) without a stall
            float wsum = ((wm0 + wm1) + (wm2 + wm3)) + ((wm4 + wm5) + (wm6 + wm7));
            asm volatile("" :: "v"(wsum));
        } else if (c > 0) {
            const int cb = (c - 1) & 1;
            // ---- layer 2: CHUNK steps for chunk c-1 ----
            CSTEP(cb, 0); CSTEP(cb, 1); CSTEP(cb, 2); CSTEP(cb, 3);
            CSTEP(cb, 4); CSTEP(cb, 5); CSTEP(cb, 6); CSTEP(cb, 7);
        }
        __syncthreads();   // chunk handoff: slist[pb] ready; buffers swap
    }
    // pipeline epilogue: last chunk's layer 2
    if (!producer) {
        const int cb = (NCH - 1) & 1;
        CSTEP(cb, 0); CSTEP(cb, 1); CSTEP(cb, 2); CSTEP(cb, 3);
        CSTEP(cb, 4); CSTEP(cb, 5); CSTEP(cb, 6); CSTEP(cb, 7);
    }

    // readout: out[b,:] = (mem2_sum/T) @ Wr.T + br ; role-local reductions
    if (producer) {
        int rcs1 = cnt1;
        for (int off = 32; off > 0; off >>= 1) rcs1 += __shfl_down(rcs1, off);
        if (lane == 0) rc1[wv] = rcs1;
    } else {
        float v = mem2s / 1000.0f;
        float p0 = v * Wr[h];
        float p1 = v * Wr[NH + h];
        int rcs2 = cnt2;
        for (int off = 32; off > 0; off >>= 1) {
            p0 += __shfl_down(p0, off);
            p1 += __shfl_down(p1, off);
            rcs2 += __shfl_down(rcs2, off);
        }
        if (lane == 0) { rp0[wv - 4] = p0; rp1[wv - 4] = p1; rc2[wv - 4] = rcs2; }
    }
    __syncthreads();
    if (tid == 0) {
        out[2 * b]     = ((rp0[0] + rp0[1]) + (rp0[2] + rp0[3])) + br[0];
        out[2 * b + 1] = ((rp1[0] + rp1[1]) + (rp1[2] + rp1[3])) + br[1];
        atomicAdd(&counts[0], (unsigned)(rc1[0] + rc1[1] + rc1[2] + rc1[3]));
        atomicAdd(&counts[1], (unsigned)(rc2[0] + rc2[1] + rc2[2] + rc2[3]));
    }
}

__global__ void snn_finalize(const unsigned int* __restrict__ counts,
                             float* __restrict__ out) {
    if (threadIdx.x < 2)
        out[512 + threadIdx.x] = (float)counts[threadIdx.x] / 65536000.0f; // T*B*256
}

extern "C" void kernel_launch(void* const* d_in, const int* in_sizes, int n_in,
                              void* d_out, int out_size, void* d_ws, size_t ws_size,
                              hipStream_t stream) {
    const float* spikes = (const float*)d_in[0];
    const float* W1     = (const float*)d_in[1];
    const float* b1     = (const float*)d_in[2];
    const float* W2     = (const float*)d_in[3];
    const float* b2     = (const float*)d_in[4];
    const float* Wr     = (const float*)d_in[5];
    const float* br     = (const float*)d_in[6];
    float* out = (float*)d_out;

    float* W2T = (float*)d_ws;                                   // 256 KB
    unsigned int* counts = (unsigned int*)((char*)d_ws + (size_t)NH * NH * sizeof(float));

    snn_prep<<<256, 256, 0, stream>>>(W2, W2T, counts);
    snn_main<<<256, 512, 0, stream>>>(spikes, W1, b1, W2T, b2, Wr, br, out, counts);
    snn_finalize<<<1, 64, 0, stream>>>(counts, out);
}